// Round 7
// baseline (239.838 us; speedup 1.0000x reference)
//
#include <hip/hip_runtime.h>
#include <math.h>
#include <float.h>

#define NHEAD 16
#define DHEAD 64
#define SEQT  2048
#define NB    2
#define CEMB  1024
#define C3    3072

typedef __attribute__((ext_vector_type(8))) short  s16x8;   // MFMA A/B frag (8 bf16)
typedef __attribute__((ext_vector_type(4))) short  s16x4;
typedef __attribute__((ext_vector_type(8))) unsigned short u16x8;
typedef __attribute__((ext_vector_type(4))) unsigned short u16x4;
typedef __attribute__((ext_vector_type(4))) float  f32x4;

__device__ __forceinline__ float sigmoidf_(float x) { return 1.0f / (1.0f + expf(-x)); }

// fp32 -> bf16 bits, round-to-nearest-even (via scalar __bf16 cast)
__device__ __forceinline__ unsigned short f2b(float f) {
    __bf16 b = (__bf16)f;
    return __builtin_bit_cast(unsigned short, b);
}

__device__ __forceinline__ void gload16(const void* g, void* l) {
    __builtin_amdgcn_global_load_lds(
        (const __attribute__((address_space(1))) void*)g,
        (__attribute__((address_space(3))) void*)l, 16, 0, 0);
}

// ---------------------------------------------------------------------------
// fp32 -> bf16 (vectorized)
// ---------------------------------------------------------------------------
__global__ __launch_bounds__(256) void convert_bf16(const float* __restrict__ s,
                                                    unsigned short* __restrict__ d)
{
    int i = (blockIdx.x * 256 + threadIdx.x) * 4;
    float4 v = *reinterpret_cast<const float4*>(s + i);
    u16x4 o = { f2b(v.x), f2b(v.y), f2b(v.z), f2b(v.w) };
    *reinterpret_cast<u16x4*>(d + i) = o;
}

// ---------------------------------------------------------------------------
// transpose + convert: src fp32 [rows][cols] -> dst bf16 [cols][rows]
// ---------------------------------------------------------------------------
__global__ __launch_bounds__(256) void transpose_convert(
    const float* __restrict__ src, unsigned short* __restrict__ dst,
    int rows, int cols)
{
    __shared__ float t[64][65];
    const int tid = threadIdx.x;
    const int c0 = blockIdx.x * 64, r0 = blockIdx.y * 64;
    const int tr = tid >> 4, tc = tid & 15;
#pragma unroll
    for (int l = 0; l < 4; ++l) {
        int r = l * 16 + tr;
        float4 vv = *reinterpret_cast<const float4*>(
            &src[(size_t)(r0 + r) * cols + c0 + tc * 4]);
        t[r][tc * 4 + 0] = vv.x; t[r][tc * 4 + 1] = vv.y;
        t[r][tc * 4 + 2] = vv.z; t[r][tc * 4 + 3] = vv.w;
    }
    __syncthreads();
#pragma unroll
    for (int l = 0; l < 4; ++l) {
        int n = l * 16 + tr;
        u16x4 o4 = { f2b(t[tc * 4 + 0][n]), f2b(t[tc * 4 + 1][n]),
                     f2b(t[tc * 4 + 2][n]), f2b(t[tc * 4 + 3][n]) };
        *reinterpret_cast<u16x4*>(&dst[(size_t)(c0 + n) * rows + r0 + tc * 4]) = o4;
    }
}

// ---------------------------------------------------------------------------
// ltab[h][rel] = log2(mask_pos(rel)*wave(rel)) - 8 ; -1e30 if mask == 0.
// (fixed softmax shift M=8 folded into the table; ratios unchanged)
// ---------------------------------------------------------------------------
__global__ void build_ltab(const float* __restrict__ sp, const float* __restrict__ pw,
                           const float* __restrict__ rw, float* __restrict__ ltab)
{
    const int h = blockIdx.x;
    const float span   = sigmoidf_(sp[h]) * 2048.0f;
    const float period = 2.0f + 2.0f * sigmoidf_(pw[h]);
    const float ratio  = -0.25f + 0.5f * sigmoidf_(rw[h]);
    const float amp    = period * 0.25f;
    const float off    = period * ratio;
    for (int rel = threadIdx.x; rel < SEQT; rel += blockDim.x) {
        float mp = fminf(fmaxf((32.0f - (float)rel + span) * 0.03125f, 0.0f), 1.0f);
        float wv = 0.5f * (cosf(6.283185307179586f * (float)rel / period) + 1.0f) * amp
                   + 0.5f + off;
        wv = fminf(fmaxf(wv, 0.0f), 1.0f);
        float m = mp * wv;
        ltab[h * SEQT + rel] = (m > 0.0f) ? (log2f(m) - 8.0f) : -1e30f;
    }
}

// ---------------------------------------------------------------------------
// MFMA GEMM: C[m][n] = sum_k A[m][k]*Wt[n][k] + bias[n]
// A bf16 [M][1024], Wt bf16 [N_][1024]. Tile 128x128, BK=64, 256 thr.
// MODE 0: scatter q/k bf16 to [B,H,T,D]; V directly transposed to [B,H,D,T]
//         (4 consecutive t per lane pack into one 8B store).
// MODE 1: fp32 row-major out.
// LDS: linear dest + inverse-swizzled global source + XOR-swizzled reads.
// ---------------------------------------------------------------------------
template<int N_, int MODE>
__global__ __launch_bounds__(256) void mfma_gemm(
    const unsigned short* __restrict__ A, const unsigned short* __restrict__ Wt,
    const float* __restrict__ bias, float* __restrict__ outf,
    unsigned short* __restrict__ qo, unsigned short* __restrict__ ko,
    unsigned short* __restrict__ vo)
{
    __shared__ unsigned short As[128 * 64];
    __shared__ unsigned short Bs[128 * 64];
    char* AsB = (char*)As;
    char* BsB = (char*)Bs;

    const int tid  = threadIdx.x;
    const int lane = tid & 63;
    const int wid  = tid >> 6;
    const int wm   = wid >> 1, wn = wid & 1;
    const int g    = lane >> 4, l15 = lane & 15;
    const int m0   = blockIdx.y * 128, n0 = blockIdx.x * 128;

    const int srow = lane >> 3;                 // row within 8-row stage chunk
    const int skel = 8 * ((lane & 7) ^ srow);   // pre-swizzled source k element
    const int swz  = (lane & 7) << 4;           // read-side XOR (row&7 == lane&7)

    f32x4 acc[4][4];
#pragma unroll
    for (int i = 0; i < 4; ++i)
#pragma unroll
        for (int j = 0; j < 4; ++j) acc[i][j] = (f32x4){0.f, 0.f, 0.f, 0.f};

    for (int kt = 0; kt < 16; ++kt) {
        const int k0 = kt * 64;
#pragma unroll
        for (int it = 0; it < 4; ++it) {
            int cc = wid * 4 + it;              // 16 chunks x 8 rows
            int row = cc * 8 + srow;
            gload16(A  + (size_t)(m0 + row) * 1024 + k0 + skel, AsB + cc * 1024);
            gload16(Wt + (size_t)(n0 + row) * 1024 + k0 + skel, BsB + cc * 1024);
        }
        __syncthreads();
#pragma unroll
        for (int kk = 0; kk < 2; ++kk) {
            s16x8 af[4], bfr[4];
#pragma unroll
            for (int mf = 0; mf < 4; ++mf) {
                int m = wm * 64 + mf * 16 + l15;
                af[mf] = *reinterpret_cast<const s16x8*>(
                    AsB + m * 128 + ((kk * 64 + g * 16) ^ swz));
            }
#pragma unroll
            for (int nf = 0; nf < 4; ++nf) {
                int n = wn * 64 + nf * 16 + l15;
                bfr[nf] = *reinterpret_cast<const s16x8*>(
                    BsB + n * 128 + ((kk * 64 + g * 16) ^ swz));
            }
#pragma unroll
            for (int mf = 0; mf < 4; ++mf)
#pragma unroll
                for (int nf = 0; nf < 4; ++nf)
                    acc[mf][nf] = __builtin_amdgcn_mfma_f32_16x16x32_bf16(
                        af[mf], bfr[nf], acc[mf][nf], 0, 0, 0);
        }
        __syncthreads();
    }

#pragma unroll
    for (int mf = 0; mf < 4; ++mf)
#pragma unroll
        for (int nf = 0; nf < 4; ++nf) {
            const int n = n0 + wn * 64 + nf * 16 + l15;
            const int mb = m0 + wm * 64 + mf * 16 + 4 * g;  // rows mb..mb+3
            const float bs = bias[n];
            if (MODE == 0) {
                const int which = n >> 10;
                const int cc = n & 1023;
                const int hh = cc >> 6, dd = cc & 63;
                const int t0 = mb & (SEQT - 1);
                const int bb = mb >> 11;          // mb mult of 4: no b-crossing
                if (which == 2) {
                    u16x4 pk;
#pragma unroll
                    for (int r = 0; r < 4; ++r) pk[r] = f2b(acc[mf][nf][r] + bs);
                    *reinterpret_cast<u16x4*>(
                        &vo[(((size_t)bb * NHEAD + hh) * DHEAD + dd) * SEQT + t0]) = pk;
                } else {
                    unsigned short* dst = (which == 0) ? qo : ko;
#pragma unroll
                    for (int r = 0; r < 4; ++r)
                        dst[(((size_t)bb * NHEAD + hh) * SEQT + t0 + r) * DHEAD + dd] =
                            f2b(acc[mf][nf][r] + bs);
                }
            } else {
#pragma unroll
                for (int r = 0; r < 4; ++r)
                    outf[(size_t)(mb + r) * N_ + n] = acc[mf][nf][r] + bs;
            }
        }
}

// ---------------------------------------------------------------------------
// MFMA flash attention, swapped QK^T (S^T = K·Q^T) so each lane's P-row is
// LANE-LOCAL: P never touches LDS; PV A-fragment packed in registers with
// k-map k(kk,g,e=4h+r) = 32kk + 16h + 4g + r, matched on the V side by two
// ds_read_b64 per (kk, d-block). Fixed-shift softmax (M=8 folded in ltab);
// denominator = ONE scalar per lane, reduced once at the end.
// Grid (T/64, B*H), 256 thr (4 waves x 16 q-rows). KV tile 64. LDS 16 KB.
// ---------------------------------------------------------------------------
__global__ __launch_bounds__(256) void attn_mfma(
    const unsigned short* __restrict__ q, const unsigned short* __restrict__ k,
    const unsigned short* __restrict__ vt, const float* __restrict__ ltab,
    const float* __restrict__ span_p, unsigned short* __restrict__ y)
{
    __shared__ unsigned short Ks[64 * 64];   // [key][d], XOR-swizzled 16B chunks
    __shared__ unsigned short Vs[64 * 64];   // [d][key], XOR-swizzled 16B chunks

    const int tid  = threadIdx.x;
    const int lane = tid & 63;
    const int w    = tid >> 6;
    const int g    = lane >> 4, l15 = lane & 15;
    const int q0   = blockIdx.x * 64;
    const int bh   = blockIdx.y, b = bh >> 4, h = bh & 15;

    const float span = sigmoidf_(span_p[h]) * 2048.0f;
    const float thr  = 32.0f + span;
    const float* lt  = ltab + h * SEQT;

    const size_t base = (size_t)bh * SEQT * DHEAD;
    const unsigned short* qb  = q  + base;
    const unsigned short* kb  = k  + base;
    const unsigned short* vtb = vt + base;

    // Q fragment (B operand): lane holds row q0+16w+l15, elems kk*32+8g+0..7
    s16x8 qa[2];
    {
        const char* qrow = (const char*)(qb + (size_t)(q0 + 16 * w + l15) * DHEAD);
        qa[0] = *reinterpret_cast<const s16x8*>(qrow + g * 16);
        qa[1] = *reinterpret_cast<const s16x8*>(qrow + 64 + g * 16);
    }

    f32x4 oa[4];
#pragma unroll
    for (int i = 0; i < 4; ++i) oa[i] = (f32x4){0.f, 0.f, 0.f, 0.f};
    float lrp = 0.f;                    // per-lane denominator partial

    const int srow = lane >> 3;
    const int skel = 8 * ((lane & 7) ^ srow);   // inverse-swizzled global src
    const int swz  = (lane & 7) << 4;           // read-side XOR
    const int qrel = q0 + 16 * w + l15;         // this lane's query row
    const float SCL = 0.18033688f;              // 0.125 * log2(e)

    for (int j0 = 0; j0 <= q0; j0 += 64) {
        if ((float)(q0 - j0 - 63) >= thr) continue;   // block-uniform skip (exact)

        __syncthreads();   // all waves done reading Ks/Vs of previous tile
#pragma unroll
        for (int it = 0; it < 2; ++it) {
            int cc = w * 2 + it;
            gload16(kb  + (size_t)(j0 + cc * 8 + srow) * DHEAD + skel,
                    (char*)Ks + cc * 1024);
            gload16(vtb + (size_t)(cc * 8 + srow) * SEQT + j0 + skel,
                    (char*)Vs + cc * 1024);
        }
        __syncthreads();

        // ---- S^T = K Q^T : st[nf][r] = S[key j0+16nf+4g+r][query qrel] ----
        f32x4 st[4];
#pragma unroll
        for (int nf = 0; nf < 4; ++nf) st[nf] = (f32x4){0.f, 0.f, 0.f, 0.f};
#pragma unroll
        for (int kk = 0; kk < 2; ++kk)
#pragma unroll
            for (int nf = 0; nf < 4; ++nf) {
                int c = nf * 16 + l15;
                s16x8 kf = *reinterpret_cast<const s16x8*>(
                    (char*)Ks + c * 128 + ((kk * 64 + g * 16) ^ swz));
                st[nf] = __builtin_amdgcn_mfma_f32_16x16x32_bf16(kf, qa[kk], st[nf], 0, 0, 0);
            }

        // ---- p = exp2(s*SCL + lt[rel]) ; rel<0 or masked -> exact 0 ----
        const int r0 = qrel - j0;       // rel = r0 - 16nf - 4g - r
        float pv[4][4];
#pragma unroll
        for (int nf = 0; nf < 4; ++nf)
#pragma unroll
            for (int r = 0; r < 4; ++r) {
                int rel = r0 - 16 * nf - 4 * g - r;
                float p = 0.f;
                if (rel >= 0) p = exp2f(fmaf(st[nf][r], SCL, lt[rel]));
                pv[nf][r] = p;
                lrp += p;
            }

        // ---- pack P into PV A-fragments (register-only) ----
        s16x8 pa[2];
#pragma unroll
        for (int kk = 0; kk < 2; ++kk)
#pragma unroll
            for (int half = 0; half < 2; ++half)
#pragma unroll
                for (int r = 0; r < 4; ++r)
                    pa[kk][half * 4 + r] = (short)f2b(pv[kk * 2 + half][r]);

        // ---- O += P V : B fragments = two b64 per (kk, d-block) from Vs ----
#pragma unroll
        for (int kk = 0; kk < 2; ++kk)
#pragma unroll
            for (int nfd = 0; nfd < 4; ++nfd) {
                const char* vrow = (const char*)Vs + (nfd * 16 + l15) * 128;
                int o1 = (kk * 64 + g * 8) ^ swz;        // keys 32kk+4g+0..3
                int o2 = (kk * 64 + g * 8 + 32) ^ swz;   // keys 32kk+16+4g+0..3
                s16x4 lo = *reinterpret_cast<const s16x4*>(vrow + o1);
                s16x4 hi = *reinterpret_cast<const s16x4*>(vrow + o2);
                s16x8 vf;
#pragma unroll
                for (int e = 0; e < 4; ++e) { vf[e] = lo[e]; vf[4 + e] = hi[e]; }
                oa[nfd] = __builtin_amdgcn_mfma_f32_16x16x32_bf16(pa[kk], vf, oa[nfd], 0, 0, 0);
            }
    }

    // ---- denominator: sum over g groups, then fetch per output row ----
    float lf = lrp;
    lf += __shfl_xor(lf, 16, 64);
    lf += __shfl_xor(lf, 32, 64);       // lf = l(query l15 of this wave-quarter)

#pragma unroll
    for (int r = 0; r < 4; ++r) {
        int src = (lane & 48) | (4 * g + r);    // a lane whose l15 == 4g+r
        float inv = 1.0f / __shfl(lf, src, 64);
        int gr = q0 + 16 * w + 4 * g + r;
#pragma unroll
        for (int nfd = 0; nfd < 4; ++nfd)
            y[((size_t)b * SEQT + gr) * CEMB + h * 64 + nfd * 16 + l15] =
                f2b(oa[nfd][r] * inv);
    }
}

// ---------------------------------------------------------------------------
// span loss
// ---------------------------------------------------------------------------
__global__ void span_loss_kernel(const float* __restrict__ sp,
                                 const float* __restrict__ pw,
                                 const float* __restrict__ rw,
                                 float* __restrict__ out)
{
    int lane = threadIdx.x;
    float val = 0.f;
    if (lane < NHEAD) {
        float span   = sigmoidf_(sp[lane]) * 2048.0f;
        float period = 2.0f + 2.0f * sigmoidf_(pw[lane]);
        float ratio  = -0.25f + 0.5f * sigmoidf_(rw[lane]);
        float ltm = 1.0f / period + 2.0f * ratio - 0.25f + 0.5f;
        val = (span + 32.0f) * ltm;
    }
#pragma unroll
    for (int o = 1; o < 16; o <<= 1) val += __shfl_xor(val, o, 64);
    if (lane == 0) out[0] = 2e-6f * val / 16.0f;
}

// ---------------------------------------------------------------------------
extern "C" void kernel_launch(void* const* d_in, const int* in_sizes, int n_in,
                              void* d_out, int out_size, void* d_ws, size_t ws_size,
                              hipStream_t stream)
{
    const float* x        = (const float*)d_in[0];
    const float* w_attn   = (const float*)d_in[1];
    const float* b_attn   = (const float*)d_in[2];
    const float* w_proj   = (const float*)d_in[3];
    const float* b_proj   = (const float*)d_in[4];
    const float* span_p   = (const float*)d_in[5];
    const float* period_w = (const float*)d_in[6];
    const float* ratio_w  = (const float*)d_in[7];

    char* ws = (char*)d_ws;
    unsigned short* xb  = (unsigned short*)(ws);                      // 8 MB [4096][1024]
    unsigned short* wT  = (unsigned short*)(ws + ((size_t)8  << 20)); // 6 MB [3072][1024]
    unsigned short* wpT = (unsigned short*)(ws + ((size_t)14 << 20)); // 2 MB [1024][1024]
    unsigned short* qb  = (unsigned short*)(ws + ((size_t)16 << 20)); // 8 MB [B,H,T,D]
    unsigned short* kb  = (unsigned short*)(ws + ((size_t)24 << 20)); // 8 MB [B,H,T,D]
    unsigned short* vt  = (unsigned short*)(ws + ((size_t)32 << 20)); // 8 MB [B,H,D,T]
    float*          lt  = (float*)         (ws + ((size_t)40 << 20)); // 128 KB [16][2048]
    unsigned short* y1  = xb;   // xb dead after QKV GEMM — alias

    float* out = (float*)d_out;
    const size_t PLANE = (size_t)NB * SEQT * CEMB;       // 4,194,304

    convert_bf16<<<4096, 256, 0, stream>>>(x, xb);
    transpose_convert<<<dim3(C3 / 64, CEMB / 64), 256, 0, stream>>>(w_attn, wT, CEMB, C3);
    transpose_convert<<<dim3(CEMB / 64, CEMB / 64), 256, 0, stream>>>(w_proj, wpT, CEMB, CEMB);
    build_ltab<<<NHEAD, 256, 0, stream>>>(span_p, period_w, ratio_w, lt);

    mfma_gemm<C3, 0><<<dim3(C3 / 128, (NB * SEQT) / 128), 256, 0, stream>>>(
        xb, wT, b_attn, nullptr, qb, kb, vt);

    attn_mfma<<<dim3(SEQT / 64, NB * NHEAD), 256, 0, stream>>>(
        qb, kb, vt, lt, span_p, y1);

    mfma_gemm<CEMB, 1><<<dim3(CEMB / 128, (NB * SEQT) / 128), 256, 0, stream>>>(
        y1, wpT, b_proj, out, nullptr, nullptr, nullptr);

    span_loss_kernel<<<1, 64, 0, stream>>>(span_p, period_w, ratio_w, out + PLANE);
}

// Round 8
// 229.663 us; speedup vs baseline: 1.0443x; 1.0443x over previous
//
#include <hip/hip_runtime.h>
#include <math.h>
#include <float.h>

#define NHEAD 16
#define DHEAD 64
#define SEQT  2048
#define NB    2
#define CEMB  1024
#define C3    3072

typedef __attribute__((ext_vector_type(8))) short  s16x8;   // MFMA A/B frag (8 bf16)
typedef __attribute__((ext_vector_type(4))) short  s16x4;
typedef __attribute__((ext_vector_type(8))) unsigned short u16x8;
typedef __attribute__((ext_vector_type(4))) unsigned short u16x4;
typedef __attribute__((ext_vector_type(4))) float  f32x4;

__device__ __forceinline__ float sigmoidf_(float x) { return 1.0f / (1.0f + expf(-x)); }

// fp32 -> bf16 bits, round-to-nearest-even (via scalar __bf16 cast)
__device__ __forceinline__ unsigned short f2b(float f) {
    __bf16 b = (__bf16)f;
    return __builtin_bit_cast(unsigned short, b);
}

__device__ __forceinline__ void gload16(const void* g, void* l) {
    __builtin_amdgcn_global_load_lds(
        (const __attribute__((address_space(1))) void*)g,
        (__attribute__((address_space(3))) void*)l, 16, 0, 0);
}

// ---------------------------------------------------------------------------
// fp32 -> bf16 (vectorized)
// ---------------------------------------------------------------------------
__global__ __launch_bounds__(256) void convert_bf16(const float* __restrict__ s,
                                                    unsigned short* __restrict__ d)
{
    int i = (blockIdx.x * 256 + threadIdx.x) * 4;
    float4 v = *reinterpret_cast<const float4*>(s + i);
    u16x4 o = { f2b(v.x), f2b(v.y), f2b(v.z), f2b(v.w) };
    *reinterpret_cast<u16x4*>(d + i) = o;
}

// ---------------------------------------------------------------------------
// transpose + convert: src fp32 [rows][cols] -> dst bf16 [cols][rows]
// ---------------------------------------------------------------------------
__global__ __launch_bounds__(256) void transpose_convert(
    const float* __restrict__ src, unsigned short* __restrict__ dst,
    int rows, int cols)
{
    __shared__ float t[64][65];
    const int tid = threadIdx.x;
    const int c0 = blockIdx.x * 64, r0 = blockIdx.y * 64;
    const int tr = tid >> 4, tc = tid & 15;
#pragma unroll
    for (int l = 0; l < 4; ++l) {
        int r = l * 16 + tr;
        float4 vv = *reinterpret_cast<const float4*>(
            &src[(size_t)(r0 + r) * cols + c0 + tc * 4]);
        t[r][tc * 4 + 0] = vv.x; t[r][tc * 4 + 1] = vv.y;
        t[r][tc * 4 + 2] = vv.z; t[r][tc * 4 + 3] = vv.w;
    }
    __syncthreads();
#pragma unroll
    for (int l = 0; l < 4; ++l) {
        int n = l * 16 + tr;
        u16x4 o4 = { f2b(t[tc * 4 + 0][n]), f2b(t[tc * 4 + 1][n]),
                     f2b(t[tc * 4 + 2][n]), f2b(t[tc * 4 + 3][n]) };
        *reinterpret_cast<u16x4*>(&dst[(size_t)(c0 + n) * rows + r0 + tc * 4]) = o4;
    }
}

// ---------------------------------------------------------------------------
// ltab[h][rel] = log2(mask_pos(rel)*wave(rel)) - 8 ; -1e30 if mask == 0.
// ---------------------------------------------------------------------------
__global__ void build_ltab(const float* __restrict__ sp, const float* __restrict__ pw,
                           const float* __restrict__ rw, float* __restrict__ ltab)
{
    const int h = blockIdx.x;
    const float span   = sigmoidf_(sp[h]) * 2048.0f;
    const float period = 2.0f + 2.0f * sigmoidf_(pw[h]);
    const float ratio  = -0.25f + 0.5f * sigmoidf_(rw[h]);
    const float amp    = period * 0.25f;
    const float off    = period * ratio;
    for (int rel = threadIdx.x; rel < SEQT; rel += blockDim.x) {
        float mp = fminf(fmaxf((32.0f - (float)rel + span) * 0.03125f, 0.0f), 1.0f);
        float wv = 0.5f * (cosf(6.283185307179586f * (float)rel / period) + 1.0f) * amp
                   + 0.5f + off;
        wv = fminf(fmaxf(wv, 0.0f), 1.0f);
        float m = mp * wv;
        ltab[h * SEQT + rel] = (m > 0.0f) ? (log2f(m) - 8.0f) : -1e30f;
    }
}

// ---------------------------------------------------------------------------
// MFMA GEMM (unchanged from R7-pass): tile 128x128, BK=64, 256 thr.
// ---------------------------------------------------------------------------
template<int N_, int MODE>
__global__ __launch_bounds__(256) void mfma_gemm(
    const unsigned short* __restrict__ A, const unsigned short* __restrict__ Wt,
    const float* __restrict__ bias, float* __restrict__ outf,
    unsigned short* __restrict__ qo, unsigned short* __restrict__ ko,
    unsigned short* __restrict__ vo)
{
    __shared__ unsigned short As[128 * 64];
    __shared__ unsigned short Bs[128 * 64];
    char* AsB = (char*)As;
    char* BsB = (char*)Bs;

    const int tid  = threadIdx.x;
    const int lane = tid & 63;
    const int wid  = tid >> 6;
    const int wm   = wid >> 1, wn = wid & 1;
    const int g    = lane >> 4, l15 = lane & 15;
    const int m0   = blockIdx.y * 128, n0 = blockIdx.x * 128;

    const int srow = lane >> 3;
    const int skel = 8 * ((lane & 7) ^ srow);
    const int swz  = (lane & 7) << 4;

    f32x4 acc[4][4];
#pragma unroll
    for (int i = 0; i < 4; ++i)
#pragma unroll
        for (int j = 0; j < 4; ++j) acc[i][j] = (f32x4){0.f, 0.f, 0.f, 0.f};

    for (int kt = 0; kt < 16; ++kt) {
        const int k0 = kt * 64;
#pragma unroll
        for (int it = 0; it < 4; ++it) {
            int cc = wid * 4 + it;
            int row = cc * 8 + srow;
            gload16(A  + (size_t)(m0 + row) * 1024 + k0 + skel, AsB + cc * 1024);
            gload16(Wt + (size_t)(n0 + row) * 1024 + k0 + skel, BsB + cc * 1024);
        }
        __syncthreads();
#pragma unroll
        for (int kk = 0; kk < 2; ++kk) {
            s16x8 af[4], bfr[4];
#pragma unroll
            for (int mf = 0; mf < 4; ++mf) {
                int m = wm * 64 + mf * 16 + l15;
                af[mf] = *reinterpret_cast<const s16x8*>(
                    AsB + m * 128 + ((kk * 64 + g * 16) ^ swz));
            }
#pragma unroll
            for (int nf = 0; nf < 4; ++nf) {
                int n = wn * 64 + nf * 16 + l15;
                bfr[nf] = *reinterpret_cast<const s16x8*>(
                    BsB + n * 128 + ((kk * 64 + g * 16) ^ swz));
            }
#pragma unroll
            for (int mf = 0; mf < 4; ++mf)
#pragma unroll
                for (int nf = 0; nf < 4; ++nf)
                    acc[mf][nf] = __builtin_amdgcn_mfma_f32_16x16x32_bf16(
                        af[mf], bfr[nf], acc[mf][nf], 0, 0, 0);
        }
        __syncthreads();
    }

#pragma unroll
    for (int mf = 0; mf < 4; ++mf)
#pragma unroll
        for (int nf = 0; nf < 4; ++nf) {
            const int n = n0 + wn * 64 + nf * 16 + l15;
            const int mb = m0 + wm * 64 + mf * 16 + 4 * g;
            const float bs = bias[n];
            if (MODE == 0) {
                const int which = n >> 10;
                const int cc = n & 1023;
                const int hh = cc >> 6, dd = cc & 63;
                const int t0 = mb & (SEQT - 1);
                const int bb = mb >> 11;
                if (which == 2) {
                    u16x4 pk;
#pragma unroll
                    for (int r = 0; r < 4; ++r) pk[r] = f2b(acc[mf][nf][r] + bs);
                    *reinterpret_cast<u16x4*>(
                        &vo[(((size_t)bb * NHEAD + hh) * DHEAD + dd) * SEQT + t0]) = pk;
                } else {
                    unsigned short* dst = (which == 0) ? qo : ko;
#pragma unroll
                    for (int r = 0; r < 4; ++r)
                        dst[(((size_t)bb * NHEAD + hh) * SEQT + t0 + r) * DHEAD + dd] =
                            f2b(acc[mf][nf][r] + bs);
                }
            } else {
#pragma unroll
                for (int r = 0; r < 4; ++r)
                    outf[(size_t)(mb + r) * N_ + n] = acc[mf][nf][r] + bs;
            }
        }
}

// ---------------------------------------------------------------------------
// MFMA flash attention — R8 changes:
//  (1) 2-phase double-buffered K/V staging: issue next tile's global_load_lds
//      before computing current; compiler's pre-barrier vmcnt(0) is the sync.
//  (2) XCD-aware block remap: all 32 q-tiles of a bh pinned to one XCD
//      (4 bh/XCD -> 2MB K/V working set in 4MB L2).
// Swapped QK^T (lane-local P), fixed-shift softmax (M=8 in ltab).
// Grid (32,32) flat-remapped internally. LDS 32 KB/block.
// ---------------------------------------------------------------------------
__global__ __launch_bounds__(256) void attn_mfma(
    const unsigned short* __restrict__ q, const unsigned short* __restrict__ k,
    const unsigned short* __restrict__ vt, const float* __restrict__ ltab,
    const float* __restrict__ span_p, unsigned short* __restrict__ y)
{
    __shared__ unsigned short Ks[2][64 * 64];   // [key][d], XOR-swizzled 16B chunks
    __shared__ unsigned short Vs[2][64 * 64];   // [d][key], XOR-swizzled 16B chunks

    const int tid  = threadIdx.x;
    const int lane = tid & 63;
    const int w    = tid >> 6;
    const int g    = lane >> 4, l15 = lane & 15;

    // XCD-aware remap (bijective: 1024 = 8 * 128)
    const int wgid = blockIdx.x + gridDim.x * blockIdx.y;
    const int xcd  = wgid & 7;
    const int idx  = wgid >> 3;
    const int bh   = (idx >> 5) * 8 + xcd;      // 4 bh per XCD
    const int qt   = idx & 31;
    const int q0   = qt * 64;
    const int b    = bh >> 4, h = bh & 15;

    const float span = sigmoidf_(span_p[h]) * 2048.0f;
    const float thr  = 32.0f + span;
    const float* lt  = ltab + h * SEQT;

    const size_t base = (size_t)bh * SEQT * DHEAD;
    const unsigned short* qb  = q  + base;
    const unsigned short* kb  = k  + base;
    const unsigned short* vtb = vt + base;

    // Q fragment (B operand): lane holds row q0+16w+l15, elems kk*32+8g+0..7
    s16x8 qa[2];
    {
        const char* qrow = (const char*)(qb + (size_t)(q0 + 16 * w + l15) * DHEAD);
        qa[0] = *reinterpret_cast<const s16x8*>(qrow + g * 16);
        qa[1] = *reinterpret_cast<const s16x8*>(qrow + 64 + g * 16);
    }

    f32x4 oa[4];
#pragma unroll
    for (int i = 0; i < 4; ++i) oa[i] = (f32x4){0.f, 0.f, 0.f, 0.f};
    float lrp = 0.f;

    const int srow = lane >> 3;
    const int skel = 8 * ((lane & 7) ^ srow);   // inverse-swizzled global src
    const int swz  = (lane & 7) << 4;           // read-side XOR
    const int qrel = q0 + 16 * w + l15;
    const float SCL = 0.18033688f;              // 0.125 * log2(e)

    // first kept tile: skip iff (q0 - j0 - 63) >= thr  <=>  j0 <= q0-63-thr
    int jstart = 0;
    {
        float lim = (float)(q0 - 63) - thr;
        if (lim >= 0.0f) jstart = (((int)lim) >> 6) * 64 + 64;
    }

    auto STAGE = [&](int bsel, int j0s) {
#pragma unroll
        for (int it = 0; it < 2; ++it) {
            int cc = w * 2 + it;
            gload16(kb  + (size_t)(j0s + cc * 8 + srow) * DHEAD + skel,
                    (char*)Ks[bsel] + cc * 1024);
            gload16(vtb + (size_t)(cc * 8 + srow) * SEQT + j0s + skel,
                    (char*)Vs[bsel] + cc * 1024);
        }
    };

    STAGE(0, jstart);
    __syncthreads();                 // compiler drains vmcnt before barrier
    int cur = 0;

    for (int j0 = jstart; j0 <= q0; j0 += 64) {
        if (j0 + 64 <= q0) STAGE(cur ^ 1, j0 + 64);   // prefetch next tile

        // ---- S^T = K Q^T : st[nf][r] = S[key j0+16nf+4g+r][query qrel] ----
        f32x4 st[4];
#pragma unroll
        for (int nf = 0; nf < 4; ++nf) st[nf] = (f32x4){0.f, 0.f, 0.f, 0.f};
#pragma unroll
        for (int kk = 0; kk < 2; ++kk)
#pragma unroll
            for (int nf = 0; nf < 4; ++nf) {
                int c = nf * 16 + l15;
                s16x8 kf = *reinterpret_cast<const s16x8*>(
                    (char*)Ks[cur] + c * 128 + ((kk * 64 + g * 16) ^ swz));
                st[nf] = __builtin_amdgcn_mfma_f32_16x16x32_bf16(kf, qa[kk], st[nf], 0, 0, 0);
            }

        // ---- p = exp2(s*SCL + lt[rel]) ; rel<0 or masked -> exact 0 ----
        const int r0 = qrel - j0;
        float pvv[4][4];
#pragma unroll
        for (int nf = 0; nf < 4; ++nf)
#pragma unroll
            for (int r = 0; r < 4; ++r) {
                int rel = r0 - 16 * nf - 4 * g - r;
                float p = 0.f;
                if (rel >= 0) p = exp2f(fmaf(st[nf][r], SCL, lt[rel]));
                pvv[nf][r] = p;
                lrp += p;
            }

        // ---- pack P into PV A-fragments (register-only) ----
        s16x8 pa[2];
#pragma unroll
        for (int kk = 0; kk < 2; ++kk)
#pragma unroll
            for (int half = 0; half < 2; ++half)
#pragma unroll
                for (int r = 0; r < 4; ++r)
                    pa[kk][half * 4 + r] = (short)f2b(pvv[kk * 2 + half][r]);

        // ---- O += P V : two b64 per (kk, d-block) from Vs ----
#pragma unroll
        for (int kk = 0; kk < 2; ++kk)
#pragma unroll
            for (int nfd = 0; nfd < 4; ++nfd) {
                const char* vrow = (const char*)Vs[cur] + (nfd * 16 + l15) * 128;
                int o1 = (kk * 64 + g * 8) ^ swz;
                int o2 = (kk * 64 + g * 8 + 32) ^ swz;
                s16x4 lo = *reinterpret_cast<const s16x4*>(vrow + o1);
                s16x4 hi = *reinterpret_cast<const s16x4*>(vrow + o2);
                s16x8 vf;
#pragma unroll
                for (int e = 0; e < 4; ++e) { vf[e] = lo[e]; vf[4 + e] = hi[e]; }
                oa[nfd] = __builtin_amdgcn_mfma_f32_16x16x32_bf16(pa[kk], vf, oa[nfd], 0, 0, 0);
            }

        __syncthreads();             // drains prefetch vmcnt + guards buffer reuse
        cur ^= 1;
    }

    // ---- denominator: sum over g groups, then fetch per output row ----
    float lf = lrp;
    lf += __shfl_xor(lf, 16, 64);
    lf += __shfl_xor(lf, 32, 64);

#pragma unroll
    for (int r = 0; r < 4; ++r) {
        int src = (lane & 48) | (4 * g + r);
        float inv = 1.0f / __shfl(lf, src, 64);
        int gr = q0 + 16 * w + 4 * g + r;
#pragma unroll
        for (int nfd = 0; nfd < 4; ++nfd)
            y[((size_t)b * SEQT + gr) * CEMB + h * 64 + nfd * 16 + l15] =
                f2b(oa[nfd][r] * inv);
    }
}

// ---------------------------------------------------------------------------
// span loss
// ---------------------------------------------------------------------------
__global__ void span_loss_kernel(const float* __restrict__ sp,
                                 const float* __restrict__ pw,
                                 const float* __restrict__ rw,
                                 float* __restrict__ out)
{
    int lane = threadIdx.x;
    float val = 0.f;
    if (lane < NHEAD) {
        float span   = sigmoidf_(sp[lane]) * 2048.0f;
        float period = 2.0f + 2.0f * sigmoidf_(pw[lane]);
        float ratio  = -0.25f + 0.5f * sigmoidf_(rw[lane]);
        float ltm = 1.0f / period + 2.0f * ratio - 0.25f + 0.5f;
        val = (span + 32.0f) * ltm;
    }
#pragma unroll
    for (int o = 1; o < 16; o <<= 1) val += __shfl_xor(val, o, 64);
    if (lane == 0) out[0] = 2e-6f * val / 16.0f;
}

// ---------------------------------------------------------------------------
extern "C" void kernel_launch(void* const* d_in, const int* in_sizes, int n_in,
                              void* d_out, int out_size, void* d_ws, size_t ws_size,
                              hipStream_t stream)
{
    const float* x        = (const float*)d_in[0];
    const float* w_attn   = (const float*)d_in[1];
    const float* b_attn   = (const float*)d_in[2];
    const float* w_proj   = (const float*)d_in[3];
    const float* b_proj   = (const float*)d_in[4];
    const float* span_p   = (const float*)d_in[5];
    const float* period_w = (const float*)d_in[6];
    const float* ratio_w  = (const float*)d_in[7];

    char* ws = (char*)d_ws;
    unsigned short* xb  = (unsigned short*)(ws);                      // 8 MB [4096][1024]
    unsigned short* wT  = (unsigned short*)(ws + ((size_t)8  << 20)); // 6 MB [3072][1024]
    unsigned short* wpT = (unsigned short*)(ws + ((size_t)14 << 20)); // 2 MB [1024][1024]
    unsigned short* qb  = (unsigned short*)(ws + ((size_t)16 << 20)); // 8 MB [B,H,T,D]
    unsigned short* kb  = (unsigned short*)(ws + ((size_t)24 << 20)); // 8 MB [B,H,T,D]
    unsigned short* vt  = (unsigned short*)(ws + ((size_t)32 << 20)); // 8 MB [B,H,D,T]
    float*          lt  = (float*)         (ws + ((size_t)40 << 20)); // 128 KB [16][2048]
    unsigned short* y1  = xb;   // xb dead after QKV GEMM — alias

    float* out = (float*)d_out;
    const size_t PLANE = (size_t)NB * SEQT * CEMB;       // 4,194,304

    convert_bf16<<<4096, 256, 0, stream>>>(x, xb);
    transpose_convert<<<dim3(C3 / 64, CEMB / 64), 256, 0, stream>>>(w_attn, wT, CEMB, C3);
    transpose_convert<<<dim3(CEMB / 64, CEMB / 64), 256, 0, stream>>>(w_proj, wpT, CEMB, CEMB);
    build_ltab<<<NHEAD, 256, 0, stream>>>(span_p, period_w, ratio_w, lt);

    mfma_gemm<C3, 0><<<dim3(C3 / 128, (NB * SEQT) / 128), 256, 0, stream>>>(
        xb, wT, b_attn, nullptr, qb, kb, vt);

    attn_mfma<<<dim3(SEQT / 64, NB * NHEAD), 256, 0, stream>>>(
        qb, kb, vt, lt, span_p, y1);

    mfma_gemm<CEMB, 1><<<dim3(CEMB / 128, (NB * SEQT) / 128), 256, 0, stream>>>(
        y1, wpT, b_proj, out, nullptr, nullptr, nullptr);

    span_loss_kernel<<<1, 64, 0, stream>>>(span_p, period_w, ratio_w, out + PLANE);
}